// Round 9
// baseline (152.474 us; speedup 1.0000x reference)
//
#include <hip/hip_runtime.h>

#define NN 8192      // nodes
#define FI 512       // in features
#define FH 512       // hidden features

typedef __attribute__((ext_vector_type(8))) short short8;
typedef __attribute__((ext_vector_type(4))) float f32x4;

__device__ __forceinline__ unsigned short f2bf(float f) {
    unsigned u = __float_as_uint(f);
    unsigned r = (u + 0x7fff + ((u >> 16) & 1)) >> 16;   // RNE
    return (unsigned short)r;
}

#define GLOAD_LDS16(g, l)                                                        \
    __builtin_amdgcn_global_load_lds((__attribute__((address_space(1))) const void*)(g), \
                                     (__attribute__((address_space(3))) void*)(l), 16, 0, 0)

// =============== K1: prep =================================================
//  blocks 0..1023    : cvt x -> bf16 (4 float4/thread)
//  blocks 1024..1087 : W1 transpose -> bf16 via padded LDS tile
//  blocks 1088..1215 : zero deg_in/deg_out/cursor/cursorT (contiguous 128 KB)
//  blocks 1216..1247 : ohe = o@Wl + bl ; h2 = b2
__global__ __launch_bounds__(256) void k_prep(const float* __restrict__ x,
                                              const float* __restrict__ W1,
                                              const float* __restrict__ o,
                                              const float* __restrict__ Wl,
                                              const float* __restrict__ bl,
                                              const float* __restrict__ b2,
                                              unsigned short* __restrict__ xb,
                                              unsigned short* __restrict__ W1t,
                                              int* __restrict__ zero_base,
                                              float* __restrict__ ohe,
                                              float* __restrict__ h2) {
    int b = blockIdx.x, t = threadIdx.x;
    if (b < 1024) {
        #pragma unroll
        for (int u = 0; u < 4; ++u) {
            int i = (b * 4 + u) * 256 + t;           // 1M float4 units total
            float4 v = reinterpret_cast<const float4*>(x)[i];
            ushort4 h;
            h.x = f2bf(v.x); h.y = f2bf(v.y); h.z = f2bf(v.z); h.w = f2bf(v.w);
            reinterpret_cast<ushort4*>(xb)[i] = h;
        }
    } else if (b < 1088) {
        __shared__ float tile[64][65];
        int bi = (b - 1024) >> 3;                    // k-tile
        int bj = (b - 1024) & 7;                     // n-tile
        int c = t & 63, r0 = t >> 6;
        #pragma unroll
        for (int rr = 0; rr < 16; ++rr) {
            int row = rr * 4 + r0;
            tile[row][c] = W1[(size_t)(bi * 64 + row) * FH + bj * 64 + c];
        }
        __syncthreads();
        #pragma unroll
        for (int rr = 0; rr < 16; ++rr) {
            int row = rr * 4 + r0;                   // n within tile
            W1t[(size_t)(bj * 64 + row) * FI + bi * 64 + c] = f2bf(tile[c][row]);
        }
    } else if (b < 1216) {
        zero_base[(b - 1088) * 256 + t] = 0;         // 32768 ints
    } else {
        int v = (b - 1216) * 256 + t;
        float4 ov = *reinterpret_cast<const float4*>(&o[(size_t)v * 4]);
        ohe[v] = ov.x * Wl[0] + ov.y * Wl[1] + ov.z * Wl[2] + ov.w * Wl[3] + bl[0];
        h2[v] = b2[0];
    }
}

// =============== K2: GEMM (blocks 0..1023) + degree count (1024..2079) ==========
__global__ __launch_bounds__(256) void k_gemmdeg(const unsigned short* __restrict__ xb,
                                                 const unsigned short* __restrict__ W1t,
                                                 unsigned char* __restrict__ h8,
                                                 const int* __restrict__ srcE,
                                                 const int* __restrict__ dstE, int E,
                                                 int* __restrict__ deg_in,
                                                 int* __restrict__ deg_out) {
    __shared__ __align__(16) unsigned short As[64 * 64];
    __shared__ __align__(16) unsigned short Bs[64 * 64];
    int bid = blockIdx.x, tid = threadIdx.x;

    if (bid >= 1024) {               // ---- degree count ----
        int i = (bid - 1024) * 256 + tid;
        if (i < E) {
            atomicAdd(&deg_in[dstE[i]], 1);
            atomicAdd(&deg_out[srcE[i]], 1);
        }
        return;
    }

    // ---- bf16 MFMA GEMM, BM=BN=BK=64; epilogue -> fp8 e4m3 ----
    int lane = tid & 63;
    int wave = tid >> 6;
    int wm = wave >> 1, wn = wave & 1;
    int bm = (bid >> 3) * 64, bn = (bid & 7) * 64;

    f32x4 acc[2][2] = {};
    int r  = lane & 15;
    int s0 = lane >> 4;

    for (int kt = 0; kt < FI / 64; ++kt) {
        #pragma unroll
        for (int t = 0; t < 2; ++t) {
            int q   = t * 256 + tid;
            int row = q >> 3;
            int sl  = q & 7;
            int sg  = sl ^ (row & 7);
            GLOAD_LDS16(xb  + (size_t)(bm + row) * FI + kt * 64 + sg * 8, As + q * 8);
            GLOAD_LDS16(W1t + (size_t)(bn + row) * FI + kt * 64 + sg * 8, Bs + q * 8);
        }
        __syncthreads();
        #pragma unroll
        for (int kc = 0; kc < 2; ++kc) {
            short8 a[2], b[2];
            #pragma unroll
            for (int m = 0; m < 2; ++m) {
                int row = wm * 32 + m * 16 + r;
                int sl  = (kc * 4 + s0) ^ (row & 7);
                a[m] = *reinterpret_cast<const short8*>(As + row * 64 + sl * 8);
            }
            #pragma unroll
            for (int n = 0; n < 2; ++n) {
                int row = wn * 32 + n * 16 + r;
                int sl  = (kc * 4 + s0) ^ (row & 7);
                b[n] = *reinterpret_cast<const short8*>(Bs + row * 64 + sl * 8);
            }
            #pragma unroll
            for (int m = 0; m < 2; ++m)
                #pragma unroll
                for (int n = 0; n < 2; ++n)
                    acc[m][n] = __builtin_amdgcn_mfma_f32_16x16x32_bf16(a[m], b[n], acc[m][n], 0, 0, 0);
        }
        __syncthreads();
    }
    #pragma unroll
    for (int m = 0; m < 2; ++m)
        #pragma unroll
        for (int n = 0; n < 2; ++n) {
            int col = bn + wn * 32 + n * 16 + (lane & 15);
            int rw0 = bm + wm * 32 + m * 16 + (lane >> 4) * 4;
            #pragma unroll
            for (int reg = 0; reg < 4; ++reg) {
                float v = acc[m][n][reg];
                int pk = __builtin_amdgcn_cvt_pk_fp8_f32(v, v, 0, false);
                h8[(size_t)(rw0 + reg) * FH + col] = (unsigned char)(pk & 0xff);
            }
        }
}

// =============== K3: per-block LDS scans + CSR/CSR^T fill ========================
// grid = (E+NN)/256 = 1056 blocks; each block recomputes both prefix scans in LDS.
__global__ __launch_bounds__(256) void k_fill(const int* __restrict__ srcE,
                                              const int* __restrict__ dstE, int E,
                                              const int* __restrict__ deg_in,
                                              const int* __restrict__ deg_out,
                                              int* __restrict__ cursor,
                                              int* __restrict__ cursorT,
                                              int* __restrict__ row_ptr,
                                              int* __restrict__ row_ptrT,
                                              int2* __restrict__ csr,
                                              int2* __restrict__ csrT) {
    __shared__ int rp[NN];
    __shared__ int rpT[NN];
    __shared__ int part[256];
    int t = threadIdx.x;
    int base = t * 32;

    // exclusive scan of (deg_in + 1)
    int s = 0;
    for (int u = 0; u < 32; ++u) s += deg_in[base + u] + 1;
    part[t] = s;
    __syncthreads();
    for (int off = 1; off < 256; off <<= 1) {
        int a = (t >= off) ? part[t - off] : 0;
        __syncthreads();
        part[t] += a;
        __syncthreads();
    }
    int run = part[t] - s;
    for (int u = 0; u < 32; ++u) { rp[base + u] = run; run += deg_in[base + u] + 1; }
    __syncthreads();

    // exclusive scan of (deg_out + 1)
    s = 0;
    for (int u = 0; u < 32; ++u) s += deg_out[base + u] + 1;
    part[t] = s;
    __syncthreads();
    for (int off = 1; off < 256; off <<= 1) {
        int a = (t >= off) ? part[t - off] : 0;
        __syncthreads();
        part[t] += a;
        __syncthreads();
    }
    run = part[t] - s;
    for (int u = 0; u < 32; ++u) { rpT[base + u] = run; run += deg_out[base + u] + 1; }
    __syncthreads();

    // block 0 publishes row_ptr arrays for K4
    if (blockIdx.x == 0) {
        for (int v = t; v < NN; v += 256) { row_ptr[v] = rp[v]; row_ptrT[v] = rpT[v]; }
        if (t == 0) { row_ptr[NN] = E + NN; row_ptrT[NN] = E + NN; }
    }

    // fill: one element per thread (grid covers E+NN exactly)
    int i = blockIdx.x * 256 + t;
    if (i < E) {
        int sv = srcE[i], d = dstE[i];
        float w = rsqrtf((float)(deg_in[sv] + 1)) * rsqrtf((float)(deg_in[d] + 1));
        int wb = __float_as_int(w);
        int p  = rp[d]  + atomicAdd(&cursor[d], 1);
        csr[p]  = make_int2(sv, wb);
        int pT = rpT[sv] + atomicAdd(&cursorT[sv], 1);
        csrT[pT] = make_int2(d, wb);
    } else {
        int v = i - E;
        float dv = rsqrtf((float)(deg_in[v] + 1));
        int wb = __float_as_int(dv * dv);
        int p  = rp[v]  + atomicAdd(&cursor[v], 1);
        csr[p]  = make_int2(v, wb);
        int pT = rpT[v] + atomicAdd(&cursorT[v], 1);
        csrT[pT] = make_int2(v, wb);
    }
}

// ---- fp8x8 accumulate helper ----
__device__ __forceinline__ void acc8(float* __restrict__ acc, uint2 rv, float w) {
    acc[0] += w * __builtin_amdgcn_cvt_f32_fp8((int)rv.x, 0);
    acc[1] += w * __builtin_amdgcn_cvt_f32_fp8((int)rv.x, 1);
    acc[2] += w * __builtin_amdgcn_cvt_f32_fp8((int)rv.x, 2);
    acc[3] += w * __builtin_amdgcn_cvt_f32_fp8((int)rv.x, 3);
    acc[4] += w * __builtin_amdgcn_cvt_f32_fp8((int)rv.y, 0);
    acc[5] += w * __builtin_amdgcn_cvt_f32_fp8((int)rv.y, 1);
    acc[6] += w * __builtin_amdgcn_cvt_f32_fp8((int)rv.y, 2);
    acc[7] += w * __builtin_amdgcn_cvt_f32_fp8((int)rv.y, 3);
}

// =============== K4: z[v] in-register, then scatter w*z into h2 =================
__global__ __launch_bounds__(256) void k_agg(const unsigned char* __restrict__ h8,
                                             const int* __restrict__ row_ptr,
                                             const int* __restrict__ row_ptrT,
                                             const int2* __restrict__ csr,
                                             const int2* __restrict__ csrT,
                                             const float* __restrict__ b1,
                                             const float* __restrict__ W2,
                                             float* __restrict__ h2) {
    int lane = threadIdx.x & 63;
    int v = blockIdx.x * 4 + (threadIdx.x >> 6);
    float acc[8] = {};
    int p0 = row_ptr[v], p1 = row_ptr[v + 1];
    for (int base = p0; base < p1; base += 64) {
        int cnt = p1 - base; if (cnt > 64) cnt = 64;
        int2 sw = (lane < cnt) ? csr[base + lane] : make_int2(0, 0);
        int j = 0;
        for (; j + 4 <= cnt; j += 4) {
            int   s0 = __shfl(sw.x, j),     s1 = __shfl(sw.x, j + 1);
            int   s2 = __shfl(sw.x, j + 2), s3 = __shfl(sw.x, j + 3);
            float w0 = __int_as_float(__shfl(sw.y, j));
            float w1 = __int_as_float(__shfl(sw.y, j + 1));
            float w2 = __int_as_float(__shfl(sw.y, j + 2));
            float w3 = __int_as_float(__shfl(sw.y, j + 3));
            uint2 r0 = *reinterpret_cast<const uint2*>(h8 + (size_t)s0 * FH + lane * 8);
            uint2 r1 = *reinterpret_cast<const uint2*>(h8 + (size_t)s1 * FH + lane * 8);
            uint2 r2 = *reinterpret_cast<const uint2*>(h8 + (size_t)s2 * FH + lane * 8);
            uint2 r3 = *reinterpret_cast<const uint2*>(h8 + (size_t)s3 * FH + lane * 8);
            acc8(acc, r0, w0);
            acc8(acc, r1, w1);
            acc8(acc, r2, w2);
            acc8(acc, r3, w3);
        }
        for (; j < cnt; ++j) {
            int   sj = __shfl(sw.x, j);
            float wj = __int_as_float(__shfl(sw.y, j));
            uint2 rj = *reinterpret_cast<const uint2*>(h8 + (size_t)sj * FH + lane * 8);
            acc8(acc, rj, wj);
        }
    }
    const float4* b4 = reinterpret_cast<const float4*>(b1 + lane * 8);
    const float4* w4 = reinterpret_cast<const float4*>(W2 + lane * 8);
    float4 b0 = b4[0], bs1 = b4[1];
    float4 w0 = w4[0], ws1 = w4[1];
    float val = fmaxf(acc[0] + b0.x, 0.f) * w0.x + fmaxf(acc[1] + b0.y, 0.f) * w0.y
              + fmaxf(acc[2] + b0.z, 0.f) * w0.z + fmaxf(acc[3] + b0.w, 0.f) * w0.w
              + fmaxf(acc[4] + bs1.x, 0.f) * ws1.x + fmaxf(acc[5] + bs1.y, 0.f) * ws1.y
              + fmaxf(acc[6] + bs1.z, 0.f) * ws1.z + fmaxf(acc[7] + bs1.w, 0.f) * ws1.w;
    #pragma unroll
    for (int off = 32; off; off >>= 1) val += __shfl_xor(val, off);
    // scatter layer-2: h2[d] += w * z[v] over v's out-edges (weights symmetric)
    int q0 = row_ptrT[v], q1 = row_ptrT[v + 1];
    for (int p = q0 + lane; p < q1; p += 64) {
        int2 sw = csrT[p];
        atomicAdd(&h2[sw.x], __int_as_float(sw.y) * val);
    }
}

// =============== K5: out[i][j] = h2[j] + ohe[i] (268 MB, nt stores) ==============
__global__ __launch_bounds__(256) void k_out(const float* __restrict__ h2,
                                             const float* __restrict__ ohe,
                                             f32x4* __restrict__ out) {
    int i0 = blockIdx.x * 4;
    int t  = threadIdx.x;
    f32x4 h[8];
    #pragma unroll
    for (int u = 0; u < 8; ++u) h[u] = reinterpret_cast<const f32x4*>(h2)[u * 256 + t];
    #pragma unroll
    for (int rr = 0; rr < 4; ++rr) {
        float oi = ohe[i0 + rr];
        f32x4* dst = out + (size_t)(i0 + rr) * 2048;
        #pragma unroll
        for (int u = 0; u < 8; ++u) {
            f32x4 w = h[u] + oi;
            __builtin_nontemporal_store(w, &dst[u * 256 + t]);
        }
    }
}

extern "C" void kernel_launch(void* const* d_in, const int* in_sizes, int n_in,
                              void* d_out, int out_size, void* d_ws, size_t ws_size,
                              hipStream_t stream) {
    const float* x  = (const float*)d_in[0];
    const float* o  = (const float*)d_in[1];
    const int*   ei = (const int*)d_in[2];
    const float* W1 = (const float*)d_in[3];
    const float* b1 = (const float*)d_in[4];
    const float* W2 = (const float*)d_in[5];
    const float* b2 = (const float*)d_in[6];
    const float* Wl = (const float*)d_in[7];
    const float* bl = (const float*)d_in[8];
    float* out = (float*)d_out;

    const int E = in_sizes[2] / 2;
    const int* src = ei;
    const int* dst = ei + E;

    // workspace carve-up (256B aligned)
    char* p = (char*)d_ws;
    auto alloc = [&](size_t bytes) {
        char* r = p;
        p += (bytes + 255) & ~(size_t)255;
        return r;
    };
    int*   deg_in   = (int*)  alloc(NN * 4);   // these four contiguous (zeroed as one span)
    int*   deg_out  = (int*)  alloc(NN * 4);
    int*   cursor   = (int*)  alloc(NN * 4);
    int*   cursorT  = (int*)  alloc(NN * 4);
    int*   row_ptr  = (int*)  alloc((NN + 1) * 4);
    int*   row_ptrT = (int*)  alloc((NN + 1) * 4);
    int2*  csr      = (int2*) alloc((size_t)(E + NN) * 8);
    int2*  csrT     = (int2*) alloc((size_t)(E + NN) * 8);
    unsigned short* xb  = (unsigned short*)alloc((size_t)NN * FI * 2);
    unsigned short* W1t = (unsigned short*)alloc((size_t)FH * FI * 2);
    unsigned char*  h8  = (unsigned char*) alloc((size_t)NN * FH);
    float* h2      = (float*)alloc(NN * 4);
    float* ohe     = (float*)alloc(NN * 4);

    k_prep   <<<1248, 256, 0, stream>>>(x, W1, o, Wl, bl, b2, xb, W1t, deg_in, ohe, h2);
    k_gemmdeg<<<1024 + (E + 255) / 256, 256, 0, stream>>>(xb, W1t, h8, src, dst, E,
                                                          deg_in, deg_out);
    k_fill   <<<(E + NN) / 256, 256, 0, stream>>>(src, dst, E, deg_in, deg_out,
                                                  cursor, cursorT, row_ptr, row_ptrT,
                                                  csr, csrT);
    k_agg    <<<NN / 4, 256, 0, stream>>>(h8, row_ptr, row_ptrT, csr, csrT, b1, W2, h2);
    k_out    <<<NN / 4, 256, 0, stream>>>(h2, ohe, (f32x4*)out);
}